// Round 5
// baseline (276.185 us; speedup 1.0000x reference)
//
#include <hip/hip_runtime.h>

// TemporalAttention: B=16, T=48, N=256, D=64, H=8, hs=8
// Kernel A: per-(b,t) K/V projections -> workspace (fp32, 100.7 MB)
// Kernel B: per-(b,2n) temporal attention, 4 q-rows/thread (LDS-amortized);
//           Q direct from global, x_att direct to global (over k workspace)
// Kernel C: fused proj1(tanh)+proj2, 8x8 register tile per thread

#define B_ 16
#define T_ 48
#define N_ 256
#define D_ 64
#define H_ 8
#define HS_ 8

__device__ __forceinline__ float rcpf(float x) { return __builtin_amdgcn_rcpf(x); }
__device__ __forceinline__ float ex2(float x) { return __builtin_amdgcn_exp2f(x); }

#define LOG2E 1.4426950408889634f

// ---------------------------------------------------------------------------
// Kernel A: k = key @ key_w[b,t] + key_b[b,t]; v likewise (blockIdx.y selects)
// ---------------------------------------------------------------------------
__global__ __launch_bounds__(256) void proj_kv_kernel(
    const float* __restrict__ key, const float* __restrict__ key_w, const float* __restrict__ key_b,
    const float* __restrict__ value, const float* __restrict__ value_w, const float* __restrict__ value_b,
    float* __restrict__ k_out, float* __restrict__ v_out)
{
    const int bt = blockIdx.x;
    const int which = blockIdx.y;
    const float* __restrict__ in = (which ? value : key) + (size_t)bt * N_ * D_;
    const float* __restrict__ w  = (which ? value_w : key_w) + (size_t)bt * D_ * D_;
    const float* __restrict__ bb = (which ? value_b : key_b) + (size_t)bt * D_;
    float* __restrict__ out = (which ? v_out : k_out) + (size_t)bt * N_ * D_;

    __shared__ float Wl[D_][D_];
    __shared__ float Xl[128][68];
    __shared__ float Bl[D_];

    const int tid = threadIdx.x;
    #pragma unroll
    for (int i = tid; i < D_ * D_; i += 256) Wl[i >> 6][i & 63] = w[i];
    if (tid < D_) Bl[tid] = bb[tid];

    const int cg = tid & 7;
    const int rg = tid >> 3;

    for (int n0 = 0; n0 < N_; n0 += 128) {
        __syncthreads();
        #pragma unroll
        for (int i = tid; i < 128 * D_ / 4; i += 256) {
            const int e = i * 4;
            *(float4*)&Xl[e >> 6][e & 63] = *(const float4*)&in[(size_t)n0 * D_ + e];
        }
        __syncthreads();

        float acc[4][8];
        #pragma unroll
        for (int j = 0; j < 4; ++j)
            #pragma unroll
            for (int i = 0; i < 8; ++i) acc[j][i] = Bl[cg * 8 + i];

        #pragma unroll 8
        for (int d = 0; d < D_; ++d) {
            const float4 w0 = *(const float4*)&Wl[d][cg * 8];
            const float4 w1 = *(const float4*)&Wl[d][cg * 8 + 4];
            #pragma unroll
            for (int j = 0; j < 4; ++j) {
                const float a = Xl[rg + 32 * j][d];
                acc[j][0] += a * w0.x; acc[j][1] += a * w0.y;
                acc[j][2] += a * w0.z; acc[j][3] += a * w0.w;
                acc[j][4] += a * w1.x; acc[j][5] += a * w1.y;
                acc[j][6] += a * w1.z; acc[j][7] += a * w1.w;
            }
        }

        #pragma unroll
        for (int j = 0; j < 4; ++j) {
            const size_t row = (size_t)(n0 + rg + 32 * j);
            *(float4*)&out[row * D_ + cg * 8]     = make_float4(acc[j][0], acc[j][1], acc[j][2], acc[j][3]);
            *(float4*)&out[row * D_ + cg * 8 + 4] = make_float4(acc[j][4], acc[j][5], acc[j][6], acc[j][7]);
        }
    }
}

// ---------------------------------------------------------------------------
// Kernel B: temporal attention. Block = (b, n0..n0+1): 192 threads.
// Thread = (nl, qg 0..11, h 0..7), owns q = qg+12j (j=0..3) for head h.
// K/V in LDS (49.2 KB -> 3 blocks/CU); Q from global (pre-scaled); x_att
// written from registers over the k workspace (slots this thread consumed).
// ---------------------------------------------------------------------------
__global__ __launch_bounds__(192) void attn_kernel(
    const float* __restrict__ query, float* __restrict__ k_xatt, const float* __restrict__ v_in,
    const float* __restrict__ rate)
{
    const int b  = blockIdx.x >> 7;
    const int n0 = (blockIdx.x & 127) * 2;

    __shared__ float K[2][T_][D_];
    __shared__ float V[2][T_][D_];

    const int tid = threadIdx.x;
    // stage K,V for both n's: 768 float4 slots per (tensor, n); n0+1 is +D_ floats
    #pragma unroll
    for (int i = tid; i < T_ * 16; i += 192) {
        const int t = i >> 4, d4 = (i & 15) * 4;
        const size_t g0 = ((size_t)(b * T_ + t) * N_ + n0) * D_ + d4;
        *(float4*)&K[0][t][d4] = *(const float4*)&k_xatt[g0];
        *(float4*)&V[0][t][d4] = *(const float4*)&v_in[g0];
        *(float4*)&K[1][t][d4] = *(const float4*)&k_xatt[g0 + D_];
        *(float4*)&V[1][t][d4] = *(const float4*)&v_in[g0 + D_];
    }
    const float rsig = rcpf(1.0f + ex2(-rate[0] * LOG2E));

    const int nl  = tid / 96;
    const int r96 = tid % 96;
    const int qg  = r96 >> 3;    // 0..11
    const int h   = r96 & 7;
    const int n   = n0 + nl;

    // load + pre-scale 4 q fragments; exponent-domain constants
    const float C1 = 0.35355339059327373f * LOG2E;
    float4 qa[4], qb[4];
    float rdn[4];
    #pragma unroll
    for (int j = 0; j < 4; ++j) {
        const int q = qg + 12 * j;
        const size_t g = ((size_t)(b * T_ + q) * N_ + n) * D_ + h * 8;
        const float4 a = *(const float4*)&query[g];
        const float4 c = *(const float4*)&query[g + 4];
        qa[j] = make_float4(-C1 * a.x, -C1 * a.y, -C1 * a.z, -C1 * a.w);
        qb[j] = make_float4(-C1 * c.x, -C1 * c.y, -C1 * c.z, -C1 * c.w);
        rdn[j] = -rsig * (float)(T_ - q) * LOG2E;
    }
    __syncthreads();

    float4 acc0[4], acc1[4];
    float ssum[4];
    #pragma unroll
    for (int j = 0; j < 4; ++j) {
        acc0[j] = make_float4(0.f, 0.f, 0.f, 0.f);
        acc1[j] = make_float4(0.f, 0.f, 0.f, 0.f);
        ssum[j] = 0.f;
    }

    #pragma unroll 2
    for (int tk = 0; tk < T_; ++tk) {
        const float4 ka = *(const float4*)&K[nl][tk][h * 8];
        const float4 kb = *(const float4*)&K[nl][tk][h * 8 + 4];
        const float4 va = *(const float4*)&V[nl][tk][h * 8];
        const float4 vb = *(const float4*)&V[nl][tk][h * 8 + 4];
        #pragma unroll
        for (int j = 0; j < 4; ++j) {
            const float dn = qa[j].x * ka.x + qa[j].y * ka.y + qa[j].z * ka.z + qa[j].w * ka.w
                           + qb[j].x * kb.x + qb[j].y * kb.y + qb[j].z * kb.z + qb[j].w * kb.w;
            const float s   = rcpf(1.0f + ex2(dn));
            const float s2  = rcpf(1.0f + ex2(s * rdn[j]));
            const float arg = s * rcpf(1.0f + s2);
            const float th  = 1.0f - 2.0f * rcpf(ex2(arg * (2.0f * LOG2E)) + 1.0f);
            const float e   = ex2(th * LOG2E);
            ssum[j] += e;
            acc0[j].x += e * va.x; acc0[j].y += e * va.y; acc0[j].z += e * va.z; acc0[j].w += e * va.w;
            acc1[j].x += e * vb.x; acc1[j].y += e * vb.y; acc1[j].z += e * vb.z; acc1[j].w += e * vb.w;
        }
    }

    // write x_att from registers (exact slots this thread's q-rows occupy)
    #pragma unroll
    for (int j = 0; j < 4; ++j) {
        const float inv = rcpf(ssum[j]);
        const int q = qg + 12 * j;
        const size_t g = ((size_t)(b * T_ + q) * N_ + n) * D_ + h * 8;
        *(float4*)&k_xatt[g]     = make_float4(acc0[j].x * inv, acc0[j].y * inv, acc0[j].z * inv, acc0[j].w * inv);
        *(float4*)&k_xatt[g + 4] = make_float4(acc1[j].x * inv, acc1[j].y * inv, acc1[j].z * inv, acc1[j].w * inv);
    }
}

// ---------------------------------------------------------------------------
// Kernel C: out = tanh(x_att @ W1^T + b1) @ W2^T + b2.
// 128 threads, 128 rows/block (1536 blocks). Thread = (rg 0..15, cg 0..7):
// rows rg+16j (j=0..7), cols cg*8..+7. d-loop step 4, X read as b128 along d.
// LDS 69.6 KB -> 2 blocks/CU.
// ---------------------------------------------------------------------------
__global__ __launch_bounds__(128) void out_proj_kernel(
    const float* __restrict__ xatt,
    const float* __restrict__ p1w, const float* __restrict__ p1b,
    const float* __restrict__ p2w, const float* __restrict__ p2b,
    float* __restrict__ out)
{
    __shared__ float X[128][68];
    __shared__ float W1t[D_][68];   // W1t[d][c] = p1w[c*64+d]
    __shared__ float W2t[D_][68];
    __shared__ float B1[D_], B2[D_];

    const int tid = threadIdx.x;
    const size_t m0 = (size_t)blockIdx.x * 128;

    #pragma unroll
    for (int i = tid; i < D_ * D_; i += 128) {
        const int c = i >> 6, d = i & 63;
        W1t[d][c] = p1w[i];
        W2t[d][c] = p2w[i];
    }
    #pragma unroll
    for (int i = tid; i < 128 * 16; i += 128) {
        const int row = i >> 4, d4 = (i & 15) * 4;
        *(float4*)&X[row][d4] = *(const float4*)&xatt[(m0 + row) * D_ + d4];
    }
    if (tid < D_) { B1[tid] = p1b[tid]; B2[tid] = p2b[tid]; }
    __syncthreads();

    const int cg = tid & 7;    // cols cg*8..+7
    const int rg = tid >> 3;   // rows rg+16j

    // ---- proj1 + tanh ----
    float x1[8][8];
    {
        float acc[8][8];
        #pragma unroll
        for (int j = 0; j < 8; ++j)
            #pragma unroll
            for (int i = 0; i < 8; ++i) acc[j][i] = B1[cg * 8 + i];

        #pragma unroll 4
        for (int d0 = 0; d0 < D_; d0 += 4) {
            float4 w0[4], w1[4];
            #pragma unroll
            for (int dd = 0; dd < 4; ++dd) {
                w0[dd] = *(const float4*)&W1t[d0 + dd][cg * 8];
                w1[dd] = *(const float4*)&W1t[d0 + dd][cg * 8 + 4];
            }
            #pragma unroll
            for (int j = 0; j < 8; ++j) {
                const float4 xv = *(const float4*)&X[rg + 16 * j][d0];
                acc[j][0] += xv.x * w0[0].x + xv.y * w0[1].x + xv.z * w0[2].x + xv.w * w0[3].x;
                acc[j][1] += xv.x * w0[0].y + xv.y * w0[1].y + xv.z * w0[2].y + xv.w * w0[3].y;
                acc[j][2] += xv.x * w0[0].z + xv.y * w0[1].z + xv.z * w0[2].z + xv.w * w0[3].z;
                acc[j][3] += xv.x * w0[0].w + xv.y * w0[1].w + xv.z * w0[2].w + xv.w * w0[3].w;
                acc[j][4] += xv.x * w1[0].x + xv.y * w1[1].x + xv.z * w1[2].x + xv.w * w1[3].x;
                acc[j][5] += xv.x * w1[0].y + xv.y * w1[1].y + xv.z * w1[2].y + xv.w * w1[3].y;
                acc[j][6] += xv.x * w1[0].z + xv.y * w1[1].z + xv.z * w1[2].z + xv.w * w1[3].z;
                acc[j][7] += xv.x * w1[0].w + xv.y * w1[1].w + xv.z * w1[2].w + xv.w * w1[3].w;
            }
        }
        #pragma unroll
        for (int j = 0; j < 8; ++j)
            #pragma unroll
            for (int i = 0; i < 8; ++i)
                x1[j][i] = 1.0f - 2.0f * rcpf(ex2(acc[j][i] * (2.0f * LOG2E)) + 1.0f);
    }
    __syncthreads();
    #pragma unroll
    for (int j = 0; j < 8; ++j) {
        *(float4*)&X[rg + 16 * j][cg * 8]     = make_float4(x1[j][0], x1[j][1], x1[j][2], x1[j][3]);
        *(float4*)&X[rg + 16 * j][cg * 8 + 4] = make_float4(x1[j][4], x1[j][5], x1[j][6], x1[j][7]);
    }
    __syncthreads();

    // ---- proj2 ----
    {
        float acc[8][8];
        #pragma unroll
        for (int j = 0; j < 8; ++j)
            #pragma unroll
            for (int i = 0; i < 8; ++i) acc[j][i] = B2[cg * 8 + i];

        #pragma unroll 4
        for (int d0 = 0; d0 < D_; d0 += 4) {
            float4 w0[4], w1[4];
            #pragma unroll
            for (int dd = 0; dd < 4; ++dd) {
                w0[dd] = *(const float4*)&W2t[d0 + dd][cg * 8];
                w1[dd] = *(const float4*)&W2t[d0 + dd][cg * 8 + 4];
            }
            #pragma unroll
            for (int j = 0; j < 8; ++j) {
                const float4 xv = *(const float4*)&X[rg + 16 * j][d0];
                acc[j][0] += xv.x * w0[0].x + xv.y * w0[1].x + xv.z * w0[2].x + xv.w * w0[3].x;
                acc[j][1] += xv.x * w0[0].y + xv.y * w0[1].y + xv.z * w0[2].y + xv.w * w0[3].y;
                acc[j][2] += xv.x * w0[0].z + xv.y * w0[1].z + xv.z * w0[2].z + xv.w * w0[3].z;
                acc[j][3] += xv.x * w0[0].w + xv.y * w0[1].w + xv.z * w0[2].w + xv.w * w0[3].w;
                acc[j][4] += xv.x * w1[0].x + xv.y * w1[1].x + xv.z * w1[2].x + xv.w * w1[3].x;
                acc[j][5] += xv.x * w1[0].y + xv.y * w1[1].y + xv.z * w1[2].y + xv.w * w1[3].y;
                acc[j][6] += xv.x * w1[0].z + xv.y * w1[1].z + xv.z * w1[2].z + xv.w * w1[3].z;
                acc[j][7] += xv.x * w1[0].w + xv.y * w1[1].w + xv.z * w1[2].w + xv.w * w1[3].w;
            }
        }
        #pragma unroll
        for (int j = 0; j < 8; ++j) {
            const size_t og = (m0 + rg + 16 * j) * D_ + cg * 8;
            *(float4*)&out[og]     = make_float4(acc[j][0], acc[j][1], acc[j][2], acc[j][3]);
            *(float4*)&out[og + 4] = make_float4(acc[j][4], acc[j][5], acc[j][6], acc[j][7]);
        }
    }
}

extern "C" void kernel_launch(void* const* d_in, const int* in_sizes, int n_in,
                              void* d_out, int out_size, void* d_ws, size_t ws_size,
                              hipStream_t stream) {
    const float* query   = (const float*)d_in[0];
    const float* key     = (const float*)d_in[1];
    const float* value   = (const float*)d_in[2];
    const float* key_w   = (const float*)d_in[3];
    const float* key_b   = (const float*)d_in[4];
    const float* value_w = (const float*)d_in[5];
    const float* value_b = (const float*)d_in[6];
    const float* p1w     = (const float*)d_in[7];
    const float* p1b     = (const float*)d_in[8];
    const float* p2w     = (const float*)d_in[9];
    const float* p2b     = (const float*)d_in[10];
    const float* rate    = (const float*)d_in[11];
    float* out = (float*)d_out;

    float* kws = (float*)d_ws;
    float* vws = kws + (size_t)B_ * T_ * N_ * D_;

    dim3 gridA(B_ * T_, 2);
    proj_kv_kernel<<<gridA, 256, 0, stream>>>(key, key_w, key_b, value, value_w, value_b, kws, vws);
    attn_kernel<<<B_ * (N_ / 2), 192, 0, stream>>>(query, kws, vws, rate);
    out_proj_kernel<<<(B_ * T_ * N_) / 128, 128, 0, stream>>>(kws, p1w, p1b, p2w, p2b, out);
}

// Round 6
// 241.611 us; speedup vs baseline: 1.1431x; 1.1431x over previous
//
#include <hip/hip_runtime.h>

// TemporalAttention: B=16, T=48, N=256, D=64, H=8, hs=8
// A: per-(b,t) K/V projections -> ws
// B: per-(b,2n) temporal attention, 3 q-rows/thread, 12 waves/CU
// W: transpose proj weights into dead v-workspace
// C: proj1(tanh)+proj2; X transposed in LDS (b32, conflict-free), W via s_load

#define B_ 16
#define T_ 48
#define N_ 256
#define D_ 64

__device__ __forceinline__ float rcpf(float x) { return __builtin_amdgcn_rcpf(x); }
__device__ __forceinline__ float ex2(float x) { return __builtin_amdgcn_exp2f(x); }
#define LOG2E 1.4426950408889634f

// ---------------------------------------------------------------------------
// Kernel A: k = key @ key_w[b,t] + key_b[b,t]; v likewise (blockIdx.y selects)
// ---------------------------------------------------------------------------
__global__ __launch_bounds__(256) void proj_kv_kernel(
    const float* __restrict__ key, const float* __restrict__ key_w, const float* __restrict__ key_b,
    const float* __restrict__ value, const float* __restrict__ value_w, const float* __restrict__ value_b,
    float* __restrict__ k_out, float* __restrict__ v_out)
{
    const int bt = blockIdx.x;
    const int which = blockIdx.y;
    const float* __restrict__ in = (which ? value : key) + (size_t)bt * N_ * D_;
    const float* __restrict__ w  = (which ? value_w : key_w) + (size_t)bt * D_ * D_;
    const float* __restrict__ bb = (which ? value_b : key_b) + (size_t)bt * D_;
    float* __restrict__ out = (which ? v_out : k_out) + (size_t)bt * N_ * D_;

    __shared__ float Wl[D_][D_];
    __shared__ float Xl[128][68];
    __shared__ float Bl[D_];

    const int tid = threadIdx.x;
    #pragma unroll
    for (int i = tid; i < D_ * D_; i += 256) Wl[i >> 6][i & 63] = w[i];
    if (tid < D_) Bl[tid] = bb[tid];

    const int cg = tid & 7;
    const int rg = tid >> 3;

    for (int n0 = 0; n0 < N_; n0 += 128) {
        __syncthreads();
        #pragma unroll
        for (int i = tid; i < 128 * D_ / 4; i += 256) {
            const int e = i * 4;
            *(float4*)&Xl[e >> 6][e & 63] = *(const float4*)&in[(size_t)n0 * D_ + e];
        }
        __syncthreads();

        float acc[4][8];
        #pragma unroll
        for (int j = 0; j < 4; ++j)
            #pragma unroll
            for (int i = 0; i < 8; ++i) acc[j][i] = Bl[cg * 8 + i];

        #pragma unroll 8
        for (int d = 0; d < D_; ++d) {
            const float4 w0 = *(const float4*)&Wl[d][cg * 8];
            const float4 w1 = *(const float4*)&Wl[d][cg * 8 + 4];
            #pragma unroll
            for (int j = 0; j < 4; ++j) {
                const float a = Xl[rg + 32 * j][d];
                acc[j][0] += a * w0.x; acc[j][1] += a * w0.y;
                acc[j][2] += a * w0.z; acc[j][3] += a * w0.w;
                acc[j][4] += a * w1.x; acc[j][5] += a * w1.y;
                acc[j][6] += a * w1.z; acc[j][7] += a * w1.w;
            }
        }

        #pragma unroll
        for (int j = 0; j < 4; ++j) {
            const size_t row = (size_t)(n0 + rg + 32 * j);
            *(float4*)&out[row * D_ + cg * 8]     = make_float4(acc[j][0], acc[j][1], acc[j][2], acc[j][3]);
            *(float4*)&out[row * D_ + cg * 8 + 4] = make_float4(acc[j][4], acc[j][5], acc[j][6], acc[j][7]);
        }
    }
}

// ---------------------------------------------------------------------------
// Kernel B: temporal attention. Block = (b, n-pair), 256 threads (4 waves).
// Thread = (nl = tid>>7, qg = (tid&127)>>3, h = tid&7); owns q = qg+16j, j=0..2.
// LDS 52.2 KB (padded 68) -> 3 blocks/CU = 12 waves/CU.
// ---------------------------------------------------------------------------
__global__ __launch_bounds__(256) void attn_kernel(
    const float* __restrict__ query, float* __restrict__ k_xatt, const float* __restrict__ v_in,
    const float* __restrict__ rate)
{
    const int b  = blockIdx.x >> 7;
    const int n0 = (blockIdx.x & 127) * 2;

    __shared__ float K[2][T_][68];
    __shared__ float V[2][T_][68];

    const int tid = threadIdx.x;
    #pragma unroll
    for (int i = tid; i < T_ * 16; i += 256) {
        const int t = i >> 4, d4 = (i & 15) * 4;
        const size_t g0 = ((size_t)(b * T_ + t) * N_ + n0) * D_ + d4;
        *(float4*)&K[0][t][d4] = *(const float4*)&k_xatt[g0];
        *(float4*)&V[0][t][d4] = *(const float4*)&v_in[g0];
        *(float4*)&K[1][t][d4] = *(const float4*)&k_xatt[g0 + D_];
        *(float4*)&V[1][t][d4] = *(const float4*)&v_in[g0 + D_];
    }
    const float rsig = rcpf(1.0f + ex2(-rate[0] * LOG2E));

    const int nl = tid >> 7;
    const int r  = tid & 127;
    const int qg = r >> 3;     // 0..15
    const int h  = r & 7;
    const int n  = n0 + nl;

    const float C1 = 0.35355339059327373f * LOG2E;
    float4 qa[3], qb[3];
    float rdn[3];
    #pragma unroll
    for (int j = 0; j < 3; ++j) {
        const int q = qg + 16 * j;
        const size_t g = ((size_t)(b * T_ + q) * N_ + n) * D_ + h * 8;
        const float4 a = *(const float4*)&query[g];
        const float4 c = *(const float4*)&query[g + 4];
        qa[j] = make_float4(-C1 * a.x, -C1 * a.y, -C1 * a.z, -C1 * a.w);
        qb[j] = make_float4(-C1 * c.x, -C1 * c.y, -C1 * c.z, -C1 * c.w);
        rdn[j] = -rsig * (float)(T_ - q) * LOG2E;
    }
    __syncthreads();

    float4 acc0[3], acc1[3];
    float ssum[3];
    #pragma unroll
    for (int j = 0; j < 3; ++j) {
        acc0[j] = make_float4(0.f, 0.f, 0.f, 0.f);
        acc1[j] = make_float4(0.f, 0.f, 0.f, 0.f);
        ssum[j] = 0.f;
    }

    #pragma unroll 2
    for (int tk = 0; tk < T_; ++tk) {
        const float4 ka = *(const float4*)&K[nl][tk][h * 8];
        const float4 kb = *(const float4*)&K[nl][tk][h * 8 + 4];
        const float4 va = *(const float4*)&V[nl][tk][h * 8];
        const float4 vb = *(const float4*)&V[nl][tk][h * 8 + 4];
        #pragma unroll
        for (int j = 0; j < 3; ++j) {
            const float dn = qa[j].x * ka.x + qa[j].y * ka.y + qa[j].z * ka.z + qa[j].w * ka.w
                           + qb[j].x * kb.x + qb[j].y * kb.y + qb[j].z * kb.z + qb[j].w * kb.w;
            const float s   = rcpf(1.0f + ex2(dn));
            const float s2  = rcpf(1.0f + ex2(s * rdn[j]));
            const float arg = s * rcpf(1.0f + s2);
            // tanh(arg), arg in (0, 0.67): Pade [3/2], err ~1e-5
            const float x2  = arg * arg;
            const float th  = arg * (15.0f + x2) * rcpf(15.0f + 6.0f * x2);
            const float e   = ex2(th * LOG2E);
            ssum[j] += e;
            acc0[j].x += e * va.x; acc0[j].y += e * va.y; acc0[j].z += e * va.z; acc0[j].w += e * va.w;
            acc1[j].x += e * vb.x; acc1[j].y += e * vb.y; acc1[j].z += e * vb.z; acc1[j].w += e * vb.w;
        }
    }

    #pragma unroll
    for (int j = 0; j < 3; ++j) {
        const float inv = rcpf(ssum[j]);
        const int q = qg + 16 * j;
        const size_t g = ((size_t)(b * T_ + q) * N_ + n) * D_ + h * 8;
        *(float4*)&k_xatt[g]     = make_float4(acc0[j].x * inv, acc0[j].y * inv, acc0[j].z * inv, acc0[j].w * inv);
        *(float4*)&k_xatt[g + 4] = make_float4(acc1[j].x * inv, acc1[j].y * inv, acc1[j].z * inv, acc1[j].w * inv);
    }
}

// ---------------------------------------------------------------------------
// Kernel W: transpose p1w/p2w (64x64) into workspace: wt[d*64+c] = p[c*64+d]
// ---------------------------------------------------------------------------
__global__ __launch_bounds__(256) void wtrans_kernel(
    const float* __restrict__ p1w, const float* __restrict__ p2w,
    float* __restrict__ w1t, float* __restrict__ w2t)
{
    const int i = blockIdx.x * 256 + threadIdx.x;
    if (i < D_ * D_) {
        const int d = i >> 6, c = i & 63;
        w1t[i] = p1w[c * 64 + d];
        w2t[i] = p2w[c * 64 + d];
    }
}

// ---------------------------------------------------------------------------
// Kernel C: out = tanh(x_att @ W1^T + b1) @ W2^T + b2.
// 256 threads (4 waves), 128 rows/block. Wave w owns cols w*16..+15 (W reads
// are wave-uniform -> s_load); lane l owns rows l, l+64.
// X transposed in LDS [d][row] (b32 reads, 2-alias free); x1 rewritten in place.
// LDS 33.8 KB -> 4 blocks/CU = 16 waves/CU.
// ---------------------------------------------------------------------------
__global__ __launch_bounds__(256) void out_proj_kernel(
    const float* __restrict__ xatt,
    const float* __restrict__ w1t, const float* __restrict__ p1b,
    const float* __restrict__ w2t, const float* __restrict__ p2b,
    float* __restrict__ out)
{
    __shared__ float Xt[D_][132];   // [d][row], pad 132 floats

    const int tid = threadIdx.x;
    const size_t m0 = (size_t)blockIdx.x * 128;

    #pragma unroll
    for (int i = tid; i < 128 * 16; i += 256) {
        const int row = i >> 4, d4 = (i & 15) * 4;
        const float4 xv = *(const float4*)&xatt[(m0 + row) * D_ + d4];
        Xt[d4 + 0][row] = xv.x;
        Xt[d4 + 1][row] = xv.y;
        Xt[d4 + 2][row] = xv.z;
        Xt[d4 + 3][row] = xv.w;
    }
    __syncthreads();

    const int l  = tid & 63;
    const int c0 = __builtin_amdgcn_readfirstlane((tid >> 6) * 16);

    // ---- proj1 + tanh ----
    float a0[16], a1[16];
    #pragma unroll
    for (int c = 0; c < 16; ++c) {
        const float bv = p1b[c0 + c];          // uniform -> s_load
        a0[c] = bv; a1[c] = bv;
    }
    for (int d = 0; d < D_; ++d) {
        const float x0 = Xt[d][l];
        const float x1 = Xt[d][l + 64];
        const float* wr = w1t + __builtin_amdgcn_readfirstlane(d * 64 + c0);
        #pragma unroll
        for (int c = 0; c < 16; ++c) {
            const float wv = wr[c];            // uniform -> s_load
            a0[c] += x0 * wv;
            a1[c] += x1 * wv;
        }
    }
    #pragma unroll
    for (int c = 0; c < 16; ++c) {
        a0[c] = 1.0f - 2.0f * rcpf(ex2(a0[c] * (2.0f * LOG2E)) + 1.0f);   // tanh
        a1[c] = 1.0f - 2.0f * rcpf(ex2(a1[c] * (2.0f * LOG2E)) + 1.0f);
    }
    __syncthreads();   // everyone done reading Xt (proj1)
    #pragma unroll
    for (int c = 0; c < 16; ++c) {
        Xt[c0 + c][l]      = a0[c];    // x1 transposed, in place
        Xt[c0 + c][l + 64] = a1[c];
    }
    __syncthreads();

    // ---- proj2 ----
    float o0[16], o1[16];
    #pragma unroll
    for (int c = 0; c < 16; ++c) {
        const float bv = p2b[c0 + c];
        o0[c] = bv; o1[c] = bv;
    }
    for (int d = 0; d < D_; ++d) {
        const float x0 = Xt[d][l];
        const float x1 = Xt[d][l + 64];
        const float* wr = w2t + __builtin_amdgcn_readfirstlane(d * 64 + c0);
        #pragma unroll
        for (int c = 0; c < 16; ++c) {
            const float wv = wr[c];
            o0[c] += x0 * wv;
            o1[c] += x1 * wv;
        }
    }
    #pragma unroll
    for (int k = 0; k < 4; ++k) {
        *(float4*)&out[(m0 + l) * D_ + c0 + 4 * k]      = make_float4(o0[4*k], o0[4*k+1], o0[4*k+2], o0[4*k+3]);
        *(float4*)&out[(m0 + l + 64) * D_ + c0 + 4 * k] = make_float4(o1[4*k], o1[4*k+1], o1[4*k+2], o1[4*k+3]);
    }
}

extern "C" void kernel_launch(void* const* d_in, const int* in_sizes, int n_in,
                              void* d_out, int out_size, void* d_ws, size_t ws_size,
                              hipStream_t stream) {
    const float* query   = (const float*)d_in[0];
    const float* key     = (const float*)d_in[1];
    const float* value   = (const float*)d_in[2];
    const float* key_w   = (const float*)d_in[3];
    const float* key_b   = (const float*)d_in[4];
    const float* value_w = (const float*)d_in[5];
    const float* value_b = (const float*)d_in[6];
    const float* p1w     = (const float*)d_in[7];
    const float* p1b     = (const float*)d_in[8];
    const float* p2w     = (const float*)d_in[9];
    const float* p2b     = (const float*)d_in[10];
    const float* rate    = (const float*)d_in[11];
    float* out = (float*)d_out;

    float* kws = (float*)d_ws;                              // k, then x_att
    float* vws = kws + (size_t)B_ * T_ * N_ * D_;           // v; dead after attn
    float* w1t = vws;                                       // transposed weights
    float* w2t = vws + D_ * D_;                             // (reuse dead v region)

    dim3 gridA(B_ * T_, 2);
    proj_kv_kernel<<<gridA, 256, 0, stream>>>(key, key_w, key_b, value, value_w, value_b, kws, vws);
    attn_kernel<<<B_ * (N_ / 2), 256, 0, stream>>>(query, kws, vws, rate);
    wtrans_kernel<<<16, 256, 0, stream>>>(p1w, p2w, w1t, w2t);
    out_proj_kernel<<<(B_ * T_ * N_) / 128, 256, 0, stream>>>(kws, w1t, p1b, w2t, p2b, out);
}

// Round 7
// 233.342 us; speedup vs baseline: 1.1836x; 1.0354x over previous
//
#include <hip/hip_runtime.h>

// TemporalAttention: B=16, T=48, N=256, D=64, H=8, hs=8
// A: per-(b,t) K/V projections -> ws
// B: per-(b,2n) temporal attention, 3 q-rows/thread, 12 waves/CU
// W: transpose proj weights into dead v-workspace
// C: proj1(tanh)+proj2; X in LDS (b128 rows), W from global (L1-resident),
//    4x8 register tile, 16 waves/CU

#define B_ 16
#define T_ 48
#define N_ 256
#define D_ 64

__device__ __forceinline__ float rcpf(float x) { return __builtin_amdgcn_rcpf(x); }
__device__ __forceinline__ float ex2(float x) { return __builtin_amdgcn_exp2f(x); }
#define LOG2E 1.4426950408889634f

// ---------------------------------------------------------------------------
// Kernel A: k = key @ key_w[b,t] + key_b[b,t]; v likewise (blockIdx.y selects)
// ---------------------------------------------------------------------------
__global__ __launch_bounds__(256) void proj_kv_kernel(
    const float* __restrict__ key, const float* __restrict__ key_w, const float* __restrict__ key_b,
    const float* __restrict__ value, const float* __restrict__ value_w, const float* __restrict__ value_b,
    float* __restrict__ k_out, float* __restrict__ v_out)
{
    const int bt = blockIdx.x;
    const int which = blockIdx.y;
    const float* __restrict__ in = (which ? value : key) + (size_t)bt * N_ * D_;
    const float* __restrict__ w  = (which ? value_w : key_w) + (size_t)bt * D_ * D_;
    const float* __restrict__ bb = (which ? value_b : key_b) + (size_t)bt * D_;
    float* __restrict__ out = (which ? v_out : k_out) + (size_t)bt * N_ * D_;

    __shared__ float Wl[D_][D_];
    __shared__ float Xl[128][68];
    __shared__ float Bl[D_];

    const int tid = threadIdx.x;
    #pragma unroll
    for (int i = tid; i < D_ * D_; i += 256) Wl[i >> 6][i & 63] = w[i];
    if (tid < D_) Bl[tid] = bb[tid];

    const int cg = tid & 7;
    const int rg = tid >> 3;

    for (int n0 = 0; n0 < N_; n0 += 128) {
        __syncthreads();
        #pragma unroll
        for (int i = tid; i < 128 * D_ / 4; i += 256) {
            const int e = i * 4;
            *(float4*)&Xl[e >> 6][e & 63] = *(const float4*)&in[(size_t)n0 * D_ + e];
        }
        __syncthreads();

        float acc[4][8];
        #pragma unroll
        for (int j = 0; j < 4; ++j)
            #pragma unroll
            for (int i = 0; i < 8; ++i) acc[j][i] = Bl[cg * 8 + i];

        #pragma unroll 8
        for (int d = 0; d < D_; ++d) {
            const float4 w0 = *(const float4*)&Wl[d][cg * 8];
            const float4 w1 = *(const float4*)&Wl[d][cg * 8 + 4];
            #pragma unroll
            for (int j = 0; j < 4; ++j) {
                const float a = Xl[rg + 32 * j][d];
                acc[j][0] += a * w0.x; acc[j][1] += a * w0.y;
                acc[j][2] += a * w0.z; acc[j][3] += a * w0.w;
                acc[j][4] += a * w1.x; acc[j][5] += a * w1.y;
                acc[j][6] += a * w1.z; acc[j][7] += a * w1.w;
            }
        }

        #pragma unroll
        for (int j = 0; j < 4; ++j) {
            const size_t row = (size_t)(n0 + rg + 32 * j);
            *(float4*)&out[row * D_ + cg * 8]     = make_float4(acc[j][0], acc[j][1], acc[j][2], acc[j][3]);
            *(float4*)&out[row * D_ + cg * 8 + 4] = make_float4(acc[j][4], acc[j][5], acc[j][6], acc[j][7]);
        }
    }
}

// ---------------------------------------------------------------------------
// Kernel B: temporal attention. Block = (b, n-pair), 256 threads (4 waves).
// Thread = (nl = tid>>7, qg = (tid&127)>>3, h = tid&7); owns q = qg+16j, j=0..2.
// LDS 52.2 KB -> 3 blocks/CU = 12 waves/CU.
// Math per element: 3 ex2 + 3 rcp (s2's rcp folded algebraically).
// ---------------------------------------------------------------------------
__global__ __launch_bounds__(256) void attn_kernel(
    const float* __restrict__ query, float* __restrict__ k_xatt, const float* __restrict__ v_in,
    const float* __restrict__ rate)
{
    const int b  = blockIdx.x >> 7;
    const int n0 = (blockIdx.x & 127) * 2;

    __shared__ float K[2][T_][68];
    __shared__ float V[2][T_][68];

    const int tid = threadIdx.x;
    #pragma unroll
    for (int i = tid; i < T_ * 16; i += 256) {
        const int t = i >> 4, d4 = (i & 15) * 4;
        const size_t g0 = ((size_t)(b * T_ + t) * N_ + n0) * D_ + d4;
        *(float4*)&K[0][t][d4] = *(const float4*)&k_xatt[g0];
        *(float4*)&V[0][t][d4] = *(const float4*)&v_in[g0];
        *(float4*)&K[1][t][d4] = *(const float4*)&k_xatt[g0 + D_];
        *(float4*)&V[1][t][d4] = *(const float4*)&v_in[g0 + D_];
    }
    const float rsig = rcpf(1.0f + ex2(-rate[0] * LOG2E));

    const int nl = tid >> 7;
    const int r  = tid & 127;
    const int qg = r >> 3;     // 0..15
    const int h  = r & 7;
    const int n  = n0 + nl;

    const float C1 = 0.35355339059327373f * LOG2E;
    float4 qa[3], qb[3];
    float rdn[3];
    #pragma unroll
    for (int j = 0; j < 3; ++j) {
        const int q = qg + 16 * j;
        const size_t g = ((size_t)(b * T_ + q) * N_ + n) * D_ + h * 8;
        const float4 a = *(const float4*)&query[g];
        const float4 c = *(const float4*)&query[g + 4];
        qa[j] = make_float4(-C1 * a.x, -C1 * a.y, -C1 * a.z, -C1 * a.w);
        qb[j] = make_float4(-C1 * c.x, -C1 * c.y, -C1 * c.z, -C1 * c.w);
        rdn[j] = -rsig * (float)(T_ - q) * LOG2E;
    }
    __syncthreads();

    float4 acc0[3], acc1[3];
    float ssum[3];
    #pragma unroll
    for (int j = 0; j < 3; ++j) {
        acc0[j] = make_float4(0.f, 0.f, 0.f, 0.f);
        acc1[j] = make_float4(0.f, 0.f, 0.f, 0.f);
        ssum[j] = 0.f;
    }

    #pragma unroll 4
    for (int tk = 0; tk < T_; ++tk) {
        const float4 ka = *(const float4*)&K[nl][tk][h * 8];
        const float4 kb = *(const float4*)&K[nl][tk][h * 8 + 4];
        const float4 va = *(const float4*)&V[nl][tk][h * 8];
        const float4 vb = *(const float4*)&V[nl][tk][h * 8 + 4];
        #pragma unroll
        for (int j = 0; j < 3; ++j) {
            const float dn = qa[j].x * ka.x + qa[j].y * ka.y + qa[j].z * ka.z + qa[j].w * ka.w
                           + qb[j].x * kb.x + qb[j].y * kb.y + qb[j].z * kb.z + qb[j].w * kb.w;
            const float E1  = ex2(dn);                 // exp(-sc)
            const float s   = rcpf(1.0f + E1);         // sigmoid(sc)
            const float E2  = ex2(s * rdn[j]);         // exp(-s*rsig*dec)
            // arg = s/(1+s2), s2 = 1/(1+E2)  ->  arg = s*(1+E2)/(2+E2)
            const float arg = s * (1.0f + E2) * rcpf(2.0f + E2);
            // tanh(arg), arg in (0, 0.67): Pade [3/2], err ~1e-5
            const float x2  = arg * arg;
            const float th  = arg * (15.0f + x2) * rcpf(15.0f + 6.0f * x2);
            const float e   = ex2(th * LOG2E);
            ssum[j] += e;
            acc0[j].x += e * va.x; acc0[j].y += e * va.y; acc0[j].z += e * va.z; acc0[j].w += e * va.w;
            acc1[j].x += e * vb.x; acc1[j].y += e * vb.y; acc1[j].z += e * vb.z; acc1[j].w += e * vb.w;
        }
    }

    #pragma unroll
    for (int j = 0; j < 3; ++j) {
        const float inv = rcpf(ssum[j]);
        const int q = qg + 16 * j;
        const size_t g = ((size_t)(b * T_ + q) * N_ + n) * D_ + h * 8;
        *(float4*)&k_xatt[g]     = make_float4(acc0[j].x * inv, acc0[j].y * inv, acc0[j].z * inv, acc0[j].w * inv);
        *(float4*)&k_xatt[g + 4] = make_float4(acc1[j].x * inv, acc1[j].y * inv, acc1[j].z * inv, acc1[j].w * inv);
    }
}

// ---------------------------------------------------------------------------
// Kernel W: transpose p1w/p2w (64x64) into workspace: wt[d*64+c] = p[c*64+d]
// ---------------------------------------------------------------------------
__global__ __launch_bounds__(256) void wtrans_kernel(
    const float* __restrict__ p1w, const float* __restrict__ p2w,
    float* __restrict__ w1t, float* __restrict__ w2t)
{
    const int i = blockIdx.x * 256 + threadIdx.x;
    if (i < D_ * D_) {
        const int d = i >> 6, c = i & 63;
        w1t[i] = p1w[c * 64 + d];
        w2t[i] = p2w[c * 64 + d];
    }
}

// ---------------------------------------------------------------------------
// Kernel C: out = tanh(x_att @ W1^T + b1) @ W2^T + b2.
// 256 threads (4 waves), 128 rows/block (1536 blocks).
// Thread = (rg 0..31, cg 0..7): rows rg+32j (j=0..3), cols cg*8..+7.
// X in LDS [128][68] (34.8 KB -> 4 blocks/CU = 16 waves/CU); W1t/W2t read
// from global (32 KB, L1/L2-resident, 8-lane broadcast per address).
// ---------------------------------------------------------------------------
__global__ __launch_bounds__(256, 4) void out_proj_kernel(
    const float* __restrict__ xatt,
    const float* __restrict__ w1t, const float* __restrict__ p1b,
    const float* __restrict__ w2t, const float* __restrict__ p2b,
    float* __restrict__ out)
{
    __shared__ float X[128][68];

    const int tid = threadIdx.x;
    const size_t m0 = (size_t)blockIdx.x * 128;

    #pragma unroll
    for (int i = tid; i < 128 * 16; i += 256) {
        const int row = i >> 4, d4 = (i & 15) * 4;
        *(float4*)&X[row][d4] = *(const float4*)&xatt[(m0 + row) * D_ + d4];
    }
    __syncthreads();

    const int cg = tid & 7;    // cols cg*8..+7
    const int rg = tid >> 3;   // rows rg+32j

    // ---- proj1 + tanh ----
    float x1[4][8];
    {
        float acc[4][8];
        #pragma unroll
        for (int i = 0; i < 8; ++i) {
            const float bv = p1b[cg * 8 + i];
            #pragma unroll
            for (int j = 0; j < 4; ++j) acc[j][i] = bv;
        }
        #pragma unroll 4
        for (int d0 = 0; d0 < D_; d0 += 4) {
            float4 w0[4], w1[4];
            #pragma unroll
            for (int dd = 0; dd < 4; ++dd) {
                w0[dd] = *(const float4*)&w1t[(d0 + dd) * 64 + cg * 8];
                w1[dd] = *(const float4*)&w1t[(d0 + dd) * 64 + cg * 8 + 4];
            }
            #pragma unroll
            for (int j = 0; j < 4; ++j) {
                const float4 xv = *(const float4*)&X[rg + 32 * j][d0];
                acc[j][0] += xv.x * w0[0].x + xv.y * w0[1].x + xv.z * w0[2].x + xv.w * w0[3].x;
                acc[j][1] += xv.x * w0[0].y + xv.y * w0[1].y + xv.z * w0[2].y + xv.w * w0[3].y;
                acc[j][2] += xv.x * w0[0].z + xv.y * w0[1].z + xv.z * w0[2].z + xv.w * w0[3].z;
                acc[j][3] += xv.x * w0[0].w + xv.y * w0[1].w + xv.z * w0[2].w + xv.w * w0[3].w;
                acc[j][4] += xv.x * w1[0].x + xv.y * w1[1].x + xv.z * w1[2].x + xv.w * w1[3].x;
                acc[j][5] += xv.x * w1[0].y + xv.y * w1[1].y + xv.z * w1[2].y + xv.w * w1[3].y;
                acc[j][6] += xv.x * w1[0].z + xv.y * w1[1].z + xv.z * w1[2].z + xv.w * w1[3].z;
                acc[j][7] += xv.x * w1[0].w + xv.y * w1[1].w + xv.z * w1[2].w + xv.w * w1[3].w;
            }
        }
        #pragma unroll
        for (int j = 0; j < 4; ++j)
            #pragma unroll
            for (int i = 0; i < 8; ++i)
                x1[j][i] = 1.0f - 2.0f * rcpf(ex2(acc[j][i] * (2.0f * LOG2E)) + 1.0f);
    }
    __syncthreads();
    #pragma unroll
    for (int j = 0; j < 4; ++j) {
        *(float4*)&X[rg + 32 * j][cg * 8]     = make_float4(x1[j][0], x1[j][1], x1[j][2], x1[j][3]);
        *(float4*)&X[rg + 32 * j][cg * 8 + 4] = make_float4(x1[j][4], x1[j][5], x1[j][6], x1[j][7]);
    }
    __syncthreads();

    // ---- proj2 ----
    {
        float acc[4][8];
        #pragma unroll
        for (int i = 0; i < 8; ++i) {
            const float bv = p2b[cg * 8 + i];
            #pragma unroll
            for (int j = 0; j < 4; ++j) acc[j][i] = bv;
        }
        #pragma unroll 4
        for (int d0 = 0; d0 < D_; d0 += 4) {
            float4 w0[4], w1[4];
            #pragma unroll
            for (int dd = 0; dd < 4; ++dd) {
                w0[dd] = *(const float4*)&w2t[(d0 + dd) * 64 + cg * 8];
                w1[dd] = *(const float4*)&w2t[(d0 + dd) * 64 + cg * 8 + 4];
            }
            #pragma unroll
            for (int j = 0; j < 4; ++j) {
                const float4 xv = *(const float4*)&X[rg + 32 * j][d0];
                acc[j][0] += xv.x * w0[0].x + xv.y * w0[1].x + xv.z * w0[2].x + xv.w * w0[3].x;
                acc[j][1] += xv.x * w0[0].y + xv.y * w0[1].y + xv.z * w0[2].y + xv.w * w0[3].y;
                acc[j][2] += xv.x * w0[0].z + xv.y * w0[1].z + xv.z * w0[2].z + xv.w * w0[3].z;
                acc[j][3] += xv.x * w0[0].w + xv.y * w0[1].w + xv.z * w0[2].w + xv.w * w0[3].w;
                acc[j][4] += xv.x * w1[0].x + xv.y * w1[1].x + xv.z * w1[2].x + xv.w * w1[3].x;
                acc[j][5] += xv.x * w1[0].y + xv.y * w1[1].y + xv.z * w1[2].y + xv.w * w1[3].y;
                acc[j][6] += xv.x * w1[0].z + xv.y * w1[1].z + xv.z * w1[2].z + xv.w * w1[3].z;
                acc[j][7] += xv.x * w1[0].w + xv.y * w1[1].w + xv.z * w1[2].w + xv.w * w1[3].w;
            }
        }
        #pragma unroll
        for (int j = 0; j < 4; ++j) {
            const size_t og = (m0 + rg + 32 * j) * D_ + cg * 8;
            *(float4*)&out[og]     = make_float4(acc[j][0], acc[j][1], acc[j][2], acc[j][3]);
            *(float4*)&out[og + 4] = make_float4(acc[j][4], acc[j][5], acc[j][6], acc[j][7]);
        }
    }
}

extern "C" void kernel_launch(void* const* d_in, const int* in_sizes, int n_in,
                              void* d_out, int out_size, void* d_ws, size_t ws_size,
                              hipStream_t stream) {
    const float* query   = (const float*)d_in[0];
    const float* key     = (const float*)d_in[1];
    const float* value   = (const float*)d_in[2];
    const float* key_w   = (const float*)d_in[3];
    const float* key_b   = (const float*)d_in[4];
    const float* value_w = (const float*)d_in[5];
    const float* value_b = (const float*)d_in[6];
    const float* p1w     = (const float*)d_in[7];
    const float* p1b     = (const float*)d_in[8];
    const float* p2w     = (const float*)d_in[9];
    const float* p2b     = (const float*)d_in[10];
    const float* rate    = (const float*)d_in[11];
    float* out = (float*)d_out;

    float* kws = (float*)d_ws;                              // k, then x_att
    float* vws = kws + (size_t)B_ * T_ * N_ * D_;           // v; dead after attn
    float* w1t = vws;                                       // transposed weights
    float* w2t = vws + D_ * D_;                             // (reuse dead v region)

    dim3 gridA(B_ * T_, 2);
    proj_kv_kernel<<<gridA, 256, 0, stream>>>(key, key_w, key_b, value, value_w, value_b, kws, vws);
    attn_kernel<<<B_ * (N_ / 2), 256, 0, stream>>>(query, kws, vws, rate);
    wtrans_kernel<<<16, 256, 0, stream>>>(p1w, p2w, w1t, w2t);
    out_proj_kernel<<<(B_ * T_ * N_) / 128, 256, 0, stream>>>(kws, w1t, p1b, w2t, p2b, out);
}